// Round 13
// baseline (13.485 us; speedup 1.0000x reference)
//
#include <hip/hip_runtime.h>

// Problem constants (fixed by setup_inputs / reference)
#define NPG    32768          // nodes per batch group
#define NTOT   131072         // B * NPG
#define MAXN   16             // max neighbors kept
#define RAD2   49             // RADIUS_PX^2, RADIUS_PX = int(0.01*640+1) = 7
#define DTMAX  10000u         // int(0.01 * 1e6)
#define NPB    256            // nodes (queries) per block
#define GX     20             // x cells (32 px each)
#define GY     16             // y cells (30 px each)
#define NCELL  (GX*GY)        // 320
#define SLOTS  16             // slots per cell (lambda ~= 1.6)

// Hash grid with PAYLOAD-IN-CELL: slot = (x | y<<10 | idx<<19, t). The query
// unpacks candidates straight from the cell row (two ds_read_b128) -- the
// dependent random sp[idx] hop of r12 is gone, and sp[] itself is deleted
// (own query coords live in registers from this thread's conversion).
__global__ __launch_bounds__(256, 2)
void tgn_edges_kernel(const float* __restrict__ pos, int* __restrict__ out) {
    __shared__ int2 cells[NCELL][SLOTS];  // packed (x|y<<10|idx<<19, t); slots >= cnt untrusted
    __shared__ int  cellcnt[NCELL];       // per-cell insert count
    __shared__ int  fin[NPB][MAXN];       // final src rows, sorted by j descending

    const int tid = threadIdx.x;
    const int b0  = blockIdx.x * NPB;

    // ---- Phase 0: init (cell counts zero, fin -1; cells array needs NO init).
    cellcnt[tid] = 0;
    if (tid < NCELL - 256) cellcnt[256 + tid] = 0;
    {
        const int4 m1 = make_int4(-1, -1, -1, -1);
        int4* f4 = reinterpret_cast<int4*>(&fin[0][0]);    // 1024 int4
        #pragma unroll
        for (int k = 0; k < 4; ++k) f4[k * 256 + tid] = m1;
    }
    __syncthreads();

    // ---- Phase 1: convert + insert window [b0-256, b0+256); keep own coords in regs.
    // s=0: lookback half, idx = tid.
    {
        const int node = b0 - 256 + tid;
        if (node >= 0) {
            const float x  = pos[3 * node + 0];
            const float y  = pos[3 * node + 1];
            const float tt = pos[3 * node + 2];
            // Must bit-match numpy float32: int32(denorm*pos + 0.001).
            // __fmul_rn/__fadd_rn prevent FMA contraction.
            const int px = (int)(__fadd_rn(__fmul_rn(640.0f,     x),  0.001f));
            const int py = (int)(__fadd_rn(__fmul_rn(480.0f,     y),  0.001f));
            const int pt = (int)(__fadd_rn(__fmul_rn(1000000.0f, tt), 0.001f));
            // Clamp cell index: px can reach 640, py 480 at the uniform's top
            // end -> would index row/col GX/GY (OOB). Spatial query range is
            // clamped to [0,639]x[0,479], so clamped inserts remain findable.
            int cx = px >> 5;              cx = cx > GX - 1 ? GX - 1 : cx;
            int cy = (py * 2185) >> 16;    cy = cy > GY - 1 ? GY - 1 : cy;
            const int cell = cy * GX + cx;
            const int slot = atomicAdd(&cellcnt[cell], 1);
            if (slot < SLOTS)
                cells[cell][slot] = make_int2(px | (py << 10) | (tid << 19), pt);
        }
    }
    // s=1: own node, idx = 256 + tid (node = b0 + tid >= 0 always).
    int qx, qy, qt;
    {
        const int node = b0 + tid;
        const float x  = pos[3 * node + 0];
        const float y  = pos[3 * node + 1];
        const float tt = pos[3 * node + 2];
        qx = (int)(__fadd_rn(__fmul_rn(640.0f,     x),  0.001f));
        qy = (int)(__fadd_rn(__fmul_rn(480.0f,     y),  0.001f));
        qt = (int)(__fadd_rn(__fmul_rn(1000000.0f, tt), 0.001f));
        if (tid != 255) {   // idx 511 can never be a candidate (j < i)
            int cx = qx >> 5;              cx = cx > GX - 1 ? GX - 1 : cx;
            int cy = (qy * 2185) >> 16;    cy = cy > GY - 1 ? GY - 1 : cy;
            const int cell = cy * GX + cx;
            const int slot = atomicAdd(&cellcnt[cell], 1);
            if (slot < SLOTS)
                cells[cell][slot] = make_int2(qx | (qy << 10) | ((256 + tid) << 19), qt);
        }
    }
    __syncthreads();

    // ---- Phase 2: query from registers. i = b0 + tid (window idx 256+tid).
    const int n = tid;
    const int xlo = qx > 7 ? qx - 7 : 0;
    const int xhi = qx < 632 ? qx + 7 : 639;
    const int ylo = qy > 7 ? qy - 7 : 0;
    const int yhi = qy < 472 ? qy + 7 : 479;
    const int cx0 = xlo >> 5,           cx1 = xhi >> 5;
    const int cy0 = (ylo * 2185) >> 16, cy1 = (yhi * 2185) >> 16;

    // Valid candidate window-idx range: covers same-batch, j>=0, i-256<=j<=i-1.
    const int boff   = b0 & (NPG - 1);
    const int idxmin = (256 - boff) > n ? (256 - boff) : n;
    const int idxmax = n + 255;

    int m = 0;   // matches found (uncapped rank)
    for (int cy = cy0; cy <= cy1; ++cy) {
        for (int cx = cx0; cx <= cx1; ++cx) {
            const int cell = cy * GX + cx;
            int c = cellcnt[cell];
            c = c > SLOTS ? SLOTS : c;
            if (c == 0) continue;
            // Branchless first 4 slots from two int4 reads (cell row is 16B-aligned).
            const int4 a4 = *reinterpret_cast<const int4*>(&cells[cell][0]);
            const int4 b4 = *reinterpret_cast<const int4*>(&cells[cell][2]);
            const int wv[4] = {a4.x, a4.z, b4.x, b4.z};
            const int wt[4] = {a4.y, a4.w, b4.y, b4.w};
            unsigned bm = 0;
            #pragma unroll
            for (int k = 0; k < 4; ++k) {
                const int w   = wv[k];
                const int idx = w >> 19;              // top bits zero -> exact
                const int dx  = qx - (w & 1023);
                const int dy  = qy - ((w >> 10) & 511);
                const unsigned dt = (unsigned)(qt - wt[k]);
                const bool ok = (k < c) & (idx >= idxmin) & (idx <= idxmax) &
                                (dx * dx + dy * dy <= RAD2) & (dt <= DTMAX);
                bm |= ok ? (1u << k) : 0u;
            }
            // Rare: insert hits into fin[n], sorted by j DESC (= reference
            // first-16-by-rank order; deterministic vs atomic insert order).
            while (bm) {
                const int k = __ffs(bm) - 1;
                bm &= bm - 1;
                const int j = b0 - 256 + (wv[k] >> 19);
                int p = m < MAXN ? m : MAXN;
                while (p > 0 && fin[n][p - 1] < j) {
                    if (p < MAXN) fin[n][p] = fin[n][p - 1];
                    --p;
                }
                if (p < MAXN) fin[n][p] = j;
                ++m;
            }
            if (c > 4) {   // rare tail
                for (int k = 4; k < c; ++k) {
                    const int2 sl = cells[cell][k];
                    const int w   = sl.x;
                    const int idx = w >> 19;
                    const int dx  = qx - (w & 1023);
                    const int dy  = qy - ((w >> 10) & 511);
                    const unsigned dt = (unsigned)(qt - sl.y);
                    if ((idx >= idxmin) & (idx <= idxmax) &
                        (dx * dx + dy * dy <= RAD2) & (dt <= DTMAX)) {
                        const int j = b0 - 256 + idx;
                        int p = m < MAXN ? m : MAXN;
                        while (p > 0 && fin[n][p - 1] < j) {
                            if (p < MAXN) fin[n][p] = fin[n][p - 1];
                            --p;
                        }
                        if (p < MAXN) fin[n][p] = j;
                        ++m;
                    }
                }
            }
        }
    }
    __syncthreads();

    // ---- Stream fin -> global: fully contiguous int4 bursts; dst derived.
    {
        const size_t base4 = (size_t)b0 * MAXN / 4;
        int4* __restrict__ gsrc = reinterpret_cast<int4*>(out) + base4;
        int4* __restrict__ gdst = reinterpret_cast<int4*>(out + (size_t)NTOT * MAXN) + base4;
        const int4* f4 = reinterpret_cast<const int4*>(&fin[0][0]);
        #pragma unroll
        for (int k = 0; k < 4; ++k) {
            const int flat = k * 256 + tid;      // flat int4 index 0..1023
            const int4 v = f4[flat];
            const int row = b0 + (flat >> 2);    // 4 int4s per output row
            int4 d;
            d.x = (v.x >= 0) ? row : -1;
            d.y = (v.y >= 0) ? row : -1;
            d.z = (v.z >= 0) ? row : -1;
            d.w = (v.w >= 0) ? row : -1;
            gsrc[flat] = v;
            gdst[flat] = d;
        }
    }
}

extern "C" void kernel_launch(void* const* d_in, const int* in_sizes, int n_in,
                              void* d_out, int out_size, void* d_ws, size_t ws_size,
                              hipStream_t stream) {
    const float* pos = (const float*)d_in[0];
    int* out = (int*)d_out;
    tgn_edges_kernel<<<NTOT / NPB, 256, 0, stream>>>(pos, out);
}

// Round 14
// 12.943 us; speedup vs baseline: 1.0419x; 1.0419x over previous
//
#include <hip/hip_runtime.h>

// Problem constants (fixed by setup_inputs / reference)
#define NPG    32768          // nodes per batch group
#define NTOT   131072         // B * NPG
#define MAXN   16             // max neighbors kept
#define RAD2   49             // RADIUS_PX^2, RADIUS_PX = int(0.01*640+1) = 7
#define DTMAX  10000u         // int(0.01 * 1e6)
#define NPB    256            // nodes (queries) per block
#define WINSZ  512            // staged window entries: [b0-256, b0+256)
#define GX     20             // x cells (32 px each)
#define GY     16             // y cells (30 px each)
#define NCELL  (GX*GY)        // 320
#define SLOTS  16             // slots per cell (lambda ~= 1.6)

// r12 structure (best measured: 13.09) + r13's OOB cell clamp + WAVE-LOCAL
// epilogue: fin row n is written only by thread n, and each wave streams out
// only its own 64 rows -> the final __syncthreads is deleted and each wave's
// 4 KB store drain overlaps other waves' still-running queries.
__global__ __launch_bounds__(256, 2)
void tgn_edges_kernel(const float* __restrict__ pos, int* __restrict__ out) {
    __shared__ int2 sp[WINSZ];            // (x|y<<16, t); window idx -> node = b0-256+idx
    __shared__ int  cellcnt[NCELL];       // per-cell insert count
    __shared__ int  cells[NCELL][SLOTS];  // per-cell window-idx lists (slots >= cnt untrusted)
    __shared__ int  fin[NPB][MAXN];       // final src rows, sorted by j descending

    const int tid  = threadIdx.x;
    const int lane = tid & 63;
    const int wid  = tid >> 6;
    const int b0   = blockIdx.x * NPB;

    // ---- Phase 0: init. cellcnt zero (block-wide, before barrier); fin -1
    // wave-locally (each wave inits its own 64 rows = 256 int4).
    cellcnt[tid] = 0;
    if (tid < NCELL - 256) cellcnt[256 + tid] = 0;
    {
        const int4 m1 = make_int4(-1, -1, -1, -1);
        int4* f4 = reinterpret_cast<int4*>(&fin[wid * 64][0]);   // wave's 256 int4
        #pragma unroll
        for (int k = 0; k < 4; ++k) f4[k * 64 + lane] = m1;
    }
    __syncthreads();

    // ---- Phase 1: stage + convert + insert nodes [b0-256, b0+256).
    #pragma unroll
    for (int s = 0; s < 2; ++s) {
        const int idx  = s * 256 + tid;
        const int node = b0 - 256 + idx;
        int2 v = make_int2(0, 0);
        if (node >= 0) {
            const float x  = pos[3 * node + 0];
            const float y  = pos[3 * node + 1];
            const float tt = pos[3 * node + 2];
            // Must bit-match numpy float32: int32(denorm*pos + 0.001).
            // __fmul_rn/__fadd_rn prevent FMA contraction.
            const int px = (int)(__fadd_rn(__fmul_rn(640.0f,     x),  0.001f));
            const int py = (int)(__fadd_rn(__fmul_rn(480.0f,     y),  0.001f));
            const int pt = (int)(__fadd_rn(__fmul_rn(1000000.0f, tt), 0.001f));
            v = make_int2(px | (py << 16), pt);
            if (idx != WINSZ - 1) {   // last entry can never be a candidate (j < i)
                // Clamp cell index: px can reach 640, py 480 at the uniform's
                // top end -> row/col GX/GY would be OOB (corrupting cellcnt).
                // Query range is clamped to [0,639]x[0,479], so clamped
                // inserts remain findable.
                int cx = px >> 5;            cx = cx > GX - 1 ? GX - 1 : cx;
                int cy = (py * 2185) >> 16;  cy = cy > GY - 1 ? GY - 1 : cy;
                const int cell = cy * GX + cx;
                const int slot = atomicAdd(&cellcnt[cell], 1);
                if (slot < SLOTS) cells[cell][slot] = idx;
            }
        }
        sp[idx] = v;
    }
    __syncthreads();

    // ---- Phase 2: query. Thread = node n; i = b0 + n (window idx 256+n).
    const int n  = tid;
    const int2 pown = sp[256 + n];
    const int x  = pown.x & 0xffff;
    const int y  = pown.x >> 16;
    const int it = pown.y;

    const int xlo = x > 7 ? x - 7 : 0;
    const int xhi = x < 632 ? x + 7 : 639;
    const int ylo = y > 7 ? y - 7 : 0;
    const int yhi = y < 472 ? y + 7 : 479;
    const int cx0 = xlo >> 5,           cx1 = xhi >> 5;
    const int cy0 = (ylo * 2185) >> 16, cy1 = (yhi * 2185) >> 16;

    // Valid candidate window-idx range: covers same-batch, j>=0, i-256<=j<=i-1.
    const int boff   = b0 & (NPG - 1);
    const int idxmin = (256 - boff) > n ? (256 - boff) : n;
    const int idxmax = n + 255;

    int m = 0;   // matches found (uncapped rank)
    for (int cy = cy0; cy <= cy1; ++cy) {
        for (int cx = cx0; cx <= cx1; ++cx) {
            const int cell = cy * GX + cx;
            int c = cellcnt[cell];
            c = c > SLOTS ? SLOTS : c;
            unsigned bm = 0;   // bit k: slot k is a true match
            if (c > 0) {
                const int4 s4 = *reinterpret_cast<const int4*>(&cells[cell][0]);
                const int sl[4] = {s4.x, s4.y, s4.z, s4.w};
                #pragma unroll
                for (int k = 0; k < 4; ++k) {   // branchless first 4 slots
                    const int idx = sl[k];
                    bool ok = (k < c) & (idx >= idxmin) & (idx <= idxmax);
                    const int ii = ok ? idx : 0;     // safe LDS addr; dead if !ok
                    const int2 pj = sp[ii];
                    const int dx = x - (pj.x & 0xffff);
                    const int dy = y - (pj.x >> 16);
                    const unsigned dt = (unsigned)(it - pj.y);  // >=0: sorted, same batch
                    ok = ok & (dx * dx + dy * dy <= RAD2) & (dt <= DTMAX);
                    bm |= ok ? (1u << k) : 0u;
                }
                if (c > 4) {   // rare tail
                    for (int k = 4; k < c; ++k) {
                        const int idx = cells[cell][k];
                        bool ok = (idx >= idxmin) & (idx <= idxmax);
                        const int ii = ok ? idx : 0;
                        const int2 pj = sp[ii];
                        const int dx = x - (pj.x & 0xffff);
                        const int dy = y - (pj.x >> 16);
                        const unsigned dt = (unsigned)(it - pj.y);
                        ok = ok & (dx * dx + dy * dy <= RAD2) & (dt <= DTMAX);
                        bm |= ok ? (1u << k) : 0u;
                    }
                }
            }
            // Rare: insert matches into fin[n], sorted by j DESC (= reference
            // first-16-by-rank order; deterministic vs atomic insert order).
            while (bm) {
                const int k = __ffs(bm) - 1;
                bm &= bm - 1;
                const int j = b0 - 256 + cells[cell][k];
                int p = m < MAXN ? m : MAXN;
                while (p > 0 && fin[n][p - 1] < j) {
                    if (p < MAXN) fin[n][p] = fin[n][p - 1];
                    --p;
                }
                if (p < MAXN) fin[n][p] = j;
                ++m;
            }
        }
    }

    // ---- Wave-local stream-out (NO block barrier): each wave writes only its
    // own 64 fin rows (written by its own lanes; per-wave LDS program order
    // guarantees visibility). 4 x 1KB contiguous bursts per wave.
    {
        const size_t base4 = (size_t)b0 * MAXN / 4 + wid * 256;
        int4* __restrict__ gsrc = reinterpret_cast<int4*>(out) + base4;
        int4* __restrict__ gdst = reinterpret_cast<int4*>(out + (size_t)NTOT * MAXN) + base4;
        const int4* f4 = reinterpret_cast<const int4*>(&fin[wid * 64][0]);
        #pragma unroll
        for (int k = 0; k < 4; ++k) {
            const int flat = k * 64 + lane;               // 0..255 within wave
            const int4 v = f4[flat];
            const int row = b0 + wid * 64 + (flat >> 2);  // 4 int4s per row
            int4 d;
            d.x = (v.x >= 0) ? row : -1;
            d.y = (v.y >= 0) ? row : -1;
            d.z = (v.z >= 0) ? row : -1;
            d.w = (v.w >= 0) ? row : -1;
            gsrc[flat] = v;
            gdst[flat] = d;
        }
    }
}

extern "C" void kernel_launch(void* const* d_in, const int* in_sizes, int n_in,
                              void* d_out, int out_size, void* d_ws, size_t ws_size,
                              hipStream_t stream) {
    const float* pos = (const float*)d_in[0];
    int* out = (int*)d_out;
    tgn_edges_kernel<<<NTOT / NPB, 256, 0, stream>>>(pos, out);
}